// Round 5
// baseline (221.505 us; speedup 1.0000x reference)
//
#include <hip/hip_runtime.h>

#define EMBED 128
#define NPATH 32
#define BATCH 4096
#define DIN 768
#define C1 128
#define C2 32

// r = relu(x*wm*y + bm), componentwise; fma ordering identical to prior rounds
__device__ __forceinline__ float4 chain_step(float4 x, float4 y, float4 wm, float4 bm) {
    float4 r;
    r.x = fmaxf(fmaf(x.x * wm.x, y.x, bm.x), 0.f);
    r.y = fmaxf(fmaf(x.y * wm.y, y.y, bm.y), 0.f);
    r.z = fmaxf(fmaf(x.z * wm.z, y.z, bm.z), 0.f);
    r.w = fmaxf(fmaf(x.w * wm.w, y.w, bm.w), 0.f);
    return r;
}

// One block per (b, group). 256 threads: dl = tid&31 owns dims 4*dl..4*dl+3 (float4),
// pq = tid>>5 (0..7) owns paths p = pq, pq+8, pq+16, pq+24.
// W/Bm metapath selection via LDS lookup (ds_read_b128) instead of cndmask chains.
template<int L>
__device__ __forceinline__ void group_body(
    const int* __restrict__ ent, const int* __restrict__ mid,
    const float* __restrict__ counts, const float4* __restrict__ E4,
    float* __restrict__ h, int gcol, int* s_idx, float4* s_red,
    const float* s_W, const float* s_B)
{
    const int b = blockIdx.x;
    const int tid = threadIdx.x;
    const int dl = tid & 31;
    const int pq = tid >> 5;

    int* s_ent = s_idx;
    int* s_mid = s_idx + NPATH * (L + 1);
    float* s_cnt = (float*)(s_idx + NPATH * (2 * L + 1));

    const int* entb = ent + (size_t)b * (NPATH * (L + 1));
    const int* midb = mid + (size_t)b * (NPATH * L);
    for (int i = tid; i < NPATH * (L + 1); i += 256) s_ent[i] = entb[i];
    for (int i = tid; i < NPATH * L; i += 256) s_mid[i] = midb[i];
    if (tid < NPATH) s_cnt[tid] = counts[(size_t)b * NPATH + tid];
    __syncthreads();   // orders s_idx AND s_W/s_B staging before all reads

    float4 n1 = make_float4(0.f, 0.f, 0.f, 0.f);
    float4 n2 = make_float4(0.f, 0.f, 0.f, 0.f);

#pragma unroll 2
    for (int j = 0; j < NPATH / 8; ++j) {
        const int p = pq + 8 * j;
        int ei[L + 1], mi[L];
#pragma unroll
        for (int i = 0; i <= L; ++i) ei[i] = s_ent[p * (L + 1) + i];
#pragma unroll
        for (int i = 0; i < L; ++i) mi[i] = s_mid[p * L + i];

        // all row gathers for this path issued up front (16 B/lane)
        float4 e[L + 1];
#pragma unroll
        for (int i = 0; i <= L; ++i) e[i] = E4[(size_t)ei[i] * 32 + dl];
        const float c = s_cnt[p];

        // W/Bm fragments via LDS lookup (off the VALU pipe)
        float4 wm[L], bm[L];
#pragma unroll
        for (int i = 0; i < L; ++i) {
            wm[i] = *(const float4*)(s_W + mi[i] * EMBED + dl * 4);
            bm[i] = *(const float4*)(s_B + mi[i] * EMBED + dl * 4);
        }

        // forward
        float4 x = e[0];
#pragma unroll
        for (int i = 0; i < L; ++i)
            x = chain_step(x, e[i + 1], wm[i], bm[i]);

        // backward: y stale = E[ent_L]
        const float4 yl = e[L];
        float4 x2 = yl;
#pragma unroll
        for (int i = L - 1; i >= 0; --i)
            x2 = chain_step(x2, yl, wm[i], bm[i]);

        n1.x = fmaf(c, x.x, n1.x); n1.y = fmaf(c, x.y, n1.y);
        n1.z = fmaf(c, x.z, n1.z); n1.w = fmaf(c, x.w, n1.w);
        n2.x = fmaf(c, x2.x, n2.x); n2.y = fmaf(c, x2.y, n2.y);
        n2.z = fmaf(c, x2.z, n2.z); n2.w = fmaf(c, x2.w, n2.w);
    }

    s_red[(pq * 2 + 0) * 32 + dl] = n1;
    s_red[(pq * 2 + 1) * 32 + dl] = n2;
    __syncthreads();
    if (tid < 64) {
        const int half = tid >> 5, dq = tid & 31;
        float4 a = s_red[(0 * 2 + half) * 32 + dq];
#pragma unroll
        for (int q = 1; q < 8; ++q) {
            float4 t = s_red[(q * 2 + half) * 32 + dq];
            a.x += t.x; a.y += t.y; a.z += t.z; a.w += t.w;
        }
        float den = 0.f;
#pragma unroll
        for (int p = 0; p < NPATH; ++p) den += s_cnt[p];
        const float inv = 1.f / den;
        a.x *= inv; a.y *= inv; a.z *= inv; a.w *= inv;
        float4* hb = (float4*)(h + (size_t)b * DIN + gcol);
        hb[half * 32 + dq] = a;
    }
}

__global__ __launch_bounds__(256) void groups_kernel(
    const int* __restrict__ e1, const int* __restrict__ m1, const float* __restrict__ c1,
    const int* __restrict__ e2, const int* __restrict__ m2, const float* __restrict__ c2,
    const int* __restrict__ e3, const int* __restrict__ m3, const float* __restrict__ c3,
    const float* __restrict__ E, const float* __restrict__ W, const float* __restrict__ Bm,
    float* __restrict__ h)
{
    __shared__ int s_idx[NPATH * 7 + NPATH];
    __shared__ float4 s_red[8 * 2 * 32];              // 8 KB
    __shared__ float s_W[3 * EMBED], s_B[3 * EMBED];  // 3 KB

    const int tid = threadIdx.x;
    // FIX R4: 3*EMBED=384 > blockDim=256 — must stride, not mask.
    for (int i = tid; i < 3 * EMBED; i += 256) {
        s_W[i] = W[i];
        s_B[i] = Bm[i];
    }
    // (synced inside group_body after index staging)

    const float4* E4 = (const float4*)E;
    const int g = blockIdx.y;
    if (g == 0)      group_body<1>(e1, m1, c1, E4, h, 0,   s_idx, s_red, s_W, s_B);
    else if (g == 1) group_body<2>(e2, m2, c2, E4, h, 256, s_idx, s_red, s_W, s_B);
    else             group_body<3>(e3, m3, c3, E4, h, 512, s_idx, s_red, s_W, s_B);
}

// Fused MLP head, LDS-staged. 8 rows/block -> 512 blocks, 256 threads.
#define MROWS 8
__global__ __launch_bounds__(256) void mlp_kernel(
    const float* __restrict__ h,
    const float* __restrict__ W1, const float* __restrict__ b1,
    const float* __restrict__ W2, const float* __restrict__ b2,
    const float* __restrict__ W3, const float* __restrict__ b3,
    float* __restrict__ out)
{
    const int tid = threadIdx.x;
    const int c = tid & 127;          // layer-1 column
    const int rh = tid >> 7;          // 0..1, owns rows rh*4 .. rh*4+3
    const int row0 = blockIdx.x * MROWS;

    __shared__ float hs[MROWS * DIN];     // 24 KB
    {
        const float4* src = (const float4*)(h + (size_t)row0 * DIN);
        float4* dst = (float4*)hs;
#pragma unroll
        for (int i = 0; i < (MROWS * DIN / 4) / 256; ++i)
            dst[tid + i * 256] = src[tid + i * 256];
    }
    __syncthreads();

    float acc[4];
    const float bias1 = b1[c];
#pragma unroll
    for (int r = 0; r < 4; ++r) acc[r] = bias1;

    const float* hrow = hs + rh * 4 * DIN;
    for (int k0 = 0; k0 < DIN; k0 += 4) {
        float w0 = W1[(k0 + 0) * C1 + c];
        float w1 = W1[(k0 + 1) * C1 + c];
        float w2 = W1[(k0 + 2) * C1 + c];
        float w3 = W1[(k0 + 3) * C1 + c];
#pragma unroll
        for (int r = 0; r < 4; ++r) {
            const float4 hq = *(const float4*)(hrow + r * DIN + k0);
            acc[r] = fmaf(hq.x, w0, acc[r]);
            acc[r] = fmaf(hq.y, w1, acc[r]);
            acc[r] = fmaf(hq.z, w2, acc[r]);
            acc[r] = fmaf(hq.w, w3, acc[r]);
        }
    }

    __shared__ float h1[MROWS][C1];
#pragma unroll
    for (int r = 0; r < 4; ++r) h1[rh * 4 + r][c] = fmaxf(acc[r], 0.f);
    __syncthreads();

    __shared__ float h2[MROWS][C2];
    {
        const int r = tid >> 5;
        const int c2 = tid & 31;
        float a = b2[c2];
#pragma unroll
        for (int k = 0; k < C1; ++k)
            a = fmaf(h1[r][k], W2[k * C2 + c2], a);
        h2[r][c2] = fmaxf(a, 0.f);
    }
    __syncthreads();

    if (tid < MROWS) {
        float a = b3[0];
#pragma unroll
        for (int k = 0; k < C2; ++k)
            a = fmaf(h2[tid][k], W3[k], a);
        out[row0 + tid] = a;
    }
}

extern "C" void kernel_launch(void* const* d_in, const int* in_sizes, int n_in,
                              void* d_out, int out_size, void* d_ws, size_t ws_size,
                              hipStream_t stream) {
    const int*   ent1 = (const int*)d_in[0];
    const int*   mid1 = (const int*)d_in[1];
    const float* cnt1 = (const float*)d_in[2];
    const int*   ent2 = (const int*)d_in[3];
    const int*   mid2 = (const int*)d_in[4];
    const float* cnt2 = (const float*)d_in[5];
    const int*   ent3 = (const int*)d_in[6];
    const int*   mid3 = (const int*)d_in[7];
    const float* cnt3 = (const float*)d_in[8];
    const float* E    = (const float*)d_in[9];
    const float* W    = (const float*)d_in[10];
    const float* Bm   = (const float*)d_in[11];
    const float* W1   = (const float*)d_in[12];
    const float* b1   = (const float*)d_in[13];
    const float* W2   = (const float*)d_in[14];
    const float* b2   = (const float*)d_in[15];
    const float* W3   = (const float*)d_in[16];
    const float* b3   = (const float*)d_in[17];

    float* h = (float*)d_ws;   // [BATCH, 768]
    float* out = (float*)d_out;

    dim3 ggrid(BATCH, 3);
    groups_kernel<<<ggrid, 256, 0, stream>>>(ent1, mid1, cnt1, ent2, mid2, cnt2,
                                             ent3, mid3, cnt3, E, W, Bm, h);
    mlp_kernel<<<BATCH / MROWS, 256, 0, stream>>>(h, W1, b1, W2, b2, W3, b3, out);
}

// Round 6
// 219.416 us; speedup vs baseline: 1.0095x; 1.0095x over previous
//
#include <hip/hip_runtime.h>

#define EMBED 128
#define NPATH 32
#define BATCH 4096
#define DIN 768
#define C1 128
#define C2 32

// r = relu(x*wm*y + bm), componentwise; fma ordering identical to prior rounds
__device__ __forceinline__ float4 chain_step(float4 x, float4 y, float4 wm, float4 bm) {
    float4 r;
    r.x = fmaxf(fmaf(x.x * wm.x, y.x, bm.x), 0.f);
    r.y = fmaxf(fmaf(x.y * wm.y, y.y, bm.y), 0.f);
    r.z = fmaxf(fmaf(x.z * wm.z, y.z, bm.z), 0.f);
    r.w = fmaxf(fmaf(x.w * wm.w, y.w, bm.w), 0.f);
    return r;
}

// One block per (b, group). 256 threads: dl = tid&31 owns dims 4*dl..4*dl+3 (float4),
// pq = tid>>5 (0..7) owns paths p = pq, pq+8, pq+16, pq+24.
// R5: all 4 paths' indices register-resident up front; all (L+1)*4 gathers issued
// back-to-back before any compute -> 2x outstanding VMEM, index latency paid once.
template<int L>
__device__ __forceinline__ void group_body(
    const int* __restrict__ ent, const int* __restrict__ mid,
    const float* __restrict__ counts, const float4* __restrict__ E4,
    float* __restrict__ h, int gcol, int* s_epad, int* s_mpad, float* s_cnt,
    float4* s_red, const float* s_W, const float* s_B)
{
    const int b = blockIdx.x;
    const int tid = threadIdx.x;
    const int dl = tid & 31;
    const int pq = tid >> 5;

    // Stage indices into PADDED layout (stride 4 per path -> int4-aligned).
    const int* entb = ent + (size_t)b * (NPATH * (L + 1));
    const int* midb = mid + (size_t)b * (NPATH * L);
    for (int i = tid; i < NPATH * (L + 1); i += 256) {
        const int p = i / (L + 1), k = i - p * (L + 1);
        s_epad[p * 4 + k] = entb[i];
    }
    for (int i = tid; i < NPATH * L; i += 256) {
        const int p = i / L, k = i - p * L;
        s_mpad[p * 4 + k] = midb[i];
    }
    if (tid < NPATH) s_cnt[tid] = counts[(size_t)b * NPATH + tid];
    __syncthreads();   // also orders s_W/s_B staging

    // All 4 paths' indices -> registers (2x ds_read_b128 + 1x b32 per path).
    int4 ev[4], mv[4];
    float cv[4];
#pragma unroll
    for (int j = 0; j < 4; ++j) {
        const int p = pq + 8 * j;
        ev[j] = *(const int4*)(s_epad + p * 4);
        mv[j] = *(const int4*)(s_mpad + p * 4);
        cv[j] = s_cnt[p];
    }

    // Issue ALL gathers back-to-back (16 for L=3): 16 KB in flight per wave.
    float4 e[4][L + 1];
#pragma unroll
    for (int j = 0; j < 4; ++j) {
        const int* ej = (const int*)&ev[j];
#pragma unroll
        for (int i = 0; i <= L; ++i)
            e[j][i] = E4[(size_t)ej[i] * 32 + dl];
    }

    float4 n1 = make_float4(0.f, 0.f, 0.f, 0.f);
    float4 n2 = make_float4(0.f, 0.f, 0.f, 0.f);

#pragma unroll
    for (int j = 0; j < 4; ++j) {
        const int* mj = (const int*)&mv[j];
        float4 wm[L], bm[L];
#pragma unroll
        for (int i = 0; i < L; ++i) {
            wm[i] = *(const float4*)(s_W + mj[i] * EMBED + dl * 4);
            bm[i] = *(const float4*)(s_B + mj[i] * EMBED + dl * 4);
        }

        float4 x = e[j][0];
#pragma unroll
        for (int i = 0; i < L; ++i)
            x = chain_step(x, e[j][i + 1], wm[i], bm[i]);

        const float4 yl = e[j][L];
        float4 x2 = yl;
#pragma unroll
        for (int i = L - 1; i >= 0; --i)
            x2 = chain_step(x2, yl, wm[i], bm[i]);

        const float c = cv[j];
        n1.x = fmaf(c, x.x, n1.x); n1.y = fmaf(c, x.y, n1.y);
        n1.z = fmaf(c, x.z, n1.z); n1.w = fmaf(c, x.w, n1.w);
        n2.x = fmaf(c, x2.x, n2.x); n2.y = fmaf(c, x2.y, n2.y);
        n2.z = fmaf(c, x2.z, n2.z); n2.w = fmaf(c, x2.w, n2.w);
    }

    s_red[(pq * 2 + 0) * 32 + dl] = n1;
    s_red[(pq * 2 + 1) * 32 + dl] = n2;
    __syncthreads();
    if (tid < 64) {
        const int half = tid >> 5, dq = tid & 31;
        float4 a = s_red[(0 * 2 + half) * 32 + dq];
#pragma unroll
        for (int q = 1; q < 8; ++q) {
            float4 t = s_red[(q * 2 + half) * 32 + dq];
            a.x += t.x; a.y += t.y; a.z += t.z; a.w += t.w;
        }
        float den = 0.f;
#pragma unroll
        for (int p = 0; p < NPATH; ++p) den += s_cnt[p];
        const float inv = 1.f / den;
        a.x *= inv; a.y *= inv; a.z *= inv; a.w *= inv;
        float4* hb = (float4*)(h + (size_t)b * DIN + gcol);
        hb[half * 32 + dq] = a;
    }
}

__global__ __launch_bounds__(256, 4) void groups_kernel(
    const int* __restrict__ e1, const int* __restrict__ m1, const float* __restrict__ c1,
    const int* __restrict__ e2, const int* __restrict__ m2, const float* __restrict__ c2,
    const int* __restrict__ e3, const int* __restrict__ m3, const float* __restrict__ c3,
    const float* __restrict__ E, const float* __restrict__ W, const float* __restrict__ Bm,
    float* __restrict__ h)
{
    __shared__ int s_epad[NPATH * 4];                 // padded, int4-aligned
    __shared__ int s_mpad[NPATH * 4];
    __shared__ float s_cnt[NPATH];
    __shared__ float4 s_red[8 * 2 * 32];              // 8 KB
    __shared__ float s_W[3 * EMBED], s_B[3 * EMBED];  // 3 KB

    const int tid = threadIdx.x;
    for (int i = tid; i < 3 * EMBED; i += 256) {      // strided: 384 > 256
        s_W[i] = W[i];
        s_B[i] = Bm[i];
    }
    // (synced inside group_body after index staging)

    const float4* E4 = (const float4*)E;
    const int g = blockIdx.y;
    if (g == 0)      group_body<1>(e1, m1, c1, E4, h, 0,   s_epad, s_mpad, s_cnt, s_red, s_W, s_B);
    else if (g == 1) group_body<2>(e2, m2, c2, E4, h, 256, s_epad, s_mpad, s_cnt, s_red, s_W, s_B);
    else             group_body<3>(e3, m3, c3, E4, h, 512, s_epad, s_mpad, s_cnt, s_red, s_W, s_B);
}

// Fused MLP head, LDS-staged. 8 rows/block -> 512 blocks, 256 threads.
#define MROWS 8
__global__ __launch_bounds__(256) void mlp_kernel(
    const float* __restrict__ h,
    const float* __restrict__ W1, const float* __restrict__ b1,
    const float* __restrict__ W2, const float* __restrict__ b2,
    const float* __restrict__ W3, const float* __restrict__ b3,
    float* __restrict__ out)
{
    const int tid = threadIdx.x;
    const int c = tid & 127;
    const int rh = tid >> 7;
    const int row0 = blockIdx.x * MROWS;

    __shared__ float hs[MROWS * DIN];     // 24 KB
    {
        const float4* src = (const float4*)(h + (size_t)row0 * DIN);
        float4* dst = (float4*)hs;
#pragma unroll
        for (int i = 0; i < (MROWS * DIN / 4) / 256; ++i)
            dst[tid + i * 256] = src[tid + i * 256];
    }
    __syncthreads();

    float acc[4];
    const float bias1 = b1[c];
#pragma unroll
    for (int r = 0; r < 4; ++r) acc[r] = bias1;

    const float* hrow = hs + rh * 4 * DIN;
    for (int k0 = 0; k0 < DIN; k0 += 4) {
        float w0 = W1[(k0 + 0) * C1 + c];
        float w1 = W1[(k0 + 1) * C1 + c];
        float w2 = W1[(k0 + 2) * C1 + c];
        float w3 = W1[(k0 + 3) * C1 + c];
#pragma unroll
        for (int r = 0; r < 4; ++r) {
            const float4 hq = *(const float4*)(hrow + r * DIN + k0);
            acc[r] = fmaf(hq.x, w0, acc[r]);
            acc[r] = fmaf(hq.y, w1, acc[r]);
            acc[r] = fmaf(hq.z, w2, acc[r]);
            acc[r] = fmaf(hq.w, w3, acc[r]);
        }
    }

    __shared__ float h1[MROWS][C1];
#pragma unroll
    for (int r = 0; r < 4; ++r) h1[rh * 4 + r][c] = fmaxf(acc[r], 0.f);
    __syncthreads();

    __shared__ float h2[MROWS][C2];
    {
        const int r = tid >> 5;
        const int c2 = tid & 31;
        float a = b2[c2];
#pragma unroll
        for (int k = 0; k < C1; ++k)
            a = fmaf(h1[r][k], W2[k * C2 + c2], a);
        h2[r][c2] = fmaxf(a, 0.f);
    }
    __syncthreads();

    if (tid < MROWS) {
        float a = b3[0];
#pragma unroll
        for (int k = 0; k < C2; ++k)
            a = fmaf(h2[tid][k], W3[k], a);
        out[row0 + tid] = a;
    }
}

extern "C" void kernel_launch(void* const* d_in, const int* in_sizes, int n_in,
                              void* d_out, int out_size, void* d_ws, size_t ws_size,
                              hipStream_t stream) {
    const int*   ent1 = (const int*)d_in[0];
    const int*   mid1 = (const int*)d_in[1];
    const float* cnt1 = (const float*)d_in[2];
    const int*   ent2 = (const int*)d_in[3];
    const int*   mid2 = (const int*)d_in[4];
    const float* cnt2 = (const float*)d_in[5];
    const int*   ent3 = (const int*)d_in[6];
    const int*   mid3 = (const int*)d_in[7];
    const float* cnt3 = (const float*)d_in[8];
    const float* E    = (const float*)d_in[9];
    const float* W    = (const float*)d_in[10];
    const float* Bm   = (const float*)d_in[11];
    const float* W1   = (const float*)d_in[12];
    const float* b1   = (const float*)d_in[13];
    const float* W2   = (const float*)d_in[14];
    const float* b2   = (const float*)d_in[15];
    const float* W3   = (const float*)d_in[16];
    const float* b3   = (const float*)d_in[17];

    float* h = (float*)d_ws;   // [BATCH, 768]
    float* out = (float*)d_out;

    dim3 ggrid(BATCH, 3);
    groups_kernel<<<ggrid, 256, 0, stream>>>(ent1, mid1, cnt1, ent2, mid2, cnt2,
                                             ent3, mid3, cnt3, E, W, Bm, h);
    mlp_kernel<<<BATCH / MROWS, 256, 0, stream>>>(h, W1, b1, W2, b2, W3, b3, out);
}